// Round 1
// baseline (334.208 us; speedup 1.0000x reference)
//
#include <hip/hip_runtime.h>
#include <hip/hip_bf16.h>

// BiLSTM_2491081031886: LSTM(B=2048,T=256,F=H=128) + linear head, fused.
// One persistent block per CU; 8 batch rows/block; weights in registers as
// bf16 MFMA B-fragments; x_t and h staged in swizzled LDS; out accumulated
// online. fp32 state (c, out-acc), bf16 matmuls via mfma_f32_16x16x32_bf16.

typedef __attribute__((ext_vector_type(8))) short short8;
typedef __attribute__((ext_vector_type(4))) float f32x4;
typedef __attribute__((ext_vector_type(2))) float f32x2;

#define T_STEPS 256

__device__ __forceinline__ unsigned short f2bf(float f) {
    unsigned int u = __builtin_bit_cast(unsigned int, f);
    u += 0x7fffu + ((u >> 16) & 1u);   // RNE
    return (unsigned short)(u >> 16);
}
__device__ __forceinline__ float rcp_fast(float x) { return __builtin_amdgcn_rcpf(x); }
__device__ __forceinline__ float sigm(float x) { return rcp_fast(1.f + __expf(-x)); }
// inf-safe tanh: 1 - 2/(e^{2x}+1)
__device__ __forceinline__ float tanh_fast(float x) { return 1.f - 2.f * rcp_fast(__expf(2.f * x) + 1.f); }

__device__ __forceinline__ short8 pack8(const f32x4 a, const f32x4 b) {
    short8 v;
    v[0] = (short)f2bf(a[0]); v[1] = (short)f2bf(a[1]);
    v[2] = (short)f2bf(a[2]); v[3] = (short)f2bf(a[3]);
    v[4] = (short)f2bf(b[0]); v[5] = (short)f2bf(b[1]);
    v[6] = (short)f2bf(b[2]); v[7] = (short)f2bf(b[3]);
    return v;
}

__global__ __launch_bounds__(512, 2) void lstm_fused_kernel(
    const float* __restrict__ x,     // [2048,256,128]
    const float* __restrict__ w_ih,  // [512,128]
    const float* __restrict__ w_hh,  // [512,128]
    const float* __restrict__ b_ih,  // [512]
    const float* __restrict__ b_hh,  // [512]
    const float* __restrict__ w_lin, // [1, 256*128]
    const float* __restrict__ b_lin, // [1]
    float* __restrict__ out)         // [2048]
{
    // LDS: bf16 [16 rows][128 k], XOR-swizzled (ushort idx ^= (row&7)<<3)
    __shared__ __align__(16) unsigned short xbuf[2][16 * 128];
    __shared__ __align__(16) unsigned short hbuf[16 * 128];
    __shared__ float redout[8][8];

    const int tid  = threadIdx.x;
    const int wave = tid >> 6;      // 0..7
    const int lane = tid & 63;
    const int c16  = lane & 15;     // MFMA row/col index
    const int kq   = lane >> 4;     // 0..3 (K-quarter)
    const int row0 = blockIdx.x * 8;
    const int hid  = wave * 16 + c16;  // this lane's hidden index (0..127)

    // ---- one-time: weights -> register B-fragments (bf16) ----
    // Gate-column permutation: wave w, tile n in {i,f,g,o}, col c16
    //   logical gate G = n*128 + w*16 + c16 ; K: [0,128)=w_ih, [128,256)=w_hh
    short8 bq[8][4];
#pragma unroll
    for (int kt = 0; kt < 8; ++kt) {
#pragma unroll
        for (int n = 0; n < 4; ++n) {
            const int G  = n * 128 + wave * 16 + c16;
            const int k0 = kt * 32 + kq * 8;
            const float* src = (kt < 4) ? (w_ih + G * 128 + k0)
                                        : (w_hh + G * 128 + (k0 - 128));
            f32x4 lo = *reinterpret_cast<const f32x4*>(src);
            f32x4 hi = *reinterpret_cast<const f32x4*>(src + 4);
            bq[kt][n] = pack8(lo, hi);
        }
    }
    float bias[4];
#pragma unroll
    for (int n = 0; n < 4; ++n) {
        const int G = n * 128 + wave * 16 + c16;
        bias[n] = b_ih[G] + b_hh[G];
    }

    // ---- stage x[t=0]; zero hbuf (h0 = 0) ----
    {
        f32x2 xv = *reinterpret_cast<const f32x2*>(
            &x[(size_t)(row0 + wave) * T_STEPS * 128 + (size_t)lane * 2]);
        unsigned int pk = (unsigned int)f2bf(xv[0]) | ((unsigned int)f2bf(xv[1]) << 16);
        int idx = (wave * 128 + lane * 2) ^ ((wave & 7) << 3);
        *reinterpret_cast<unsigned int*>(&xbuf[0][idx]) = pk;
        reinterpret_cast<unsigned long long*>(hbuf)[tid] = 0ull;  // 512*8B = 4KB
    }

    float cstate[4] = {0.f, 0.f, 0.f, 0.f};
    float accout[4] = {0.f, 0.f, 0.f, 0.f};
    float wl_cur = w_lin[hid];
    __syncthreads();

    for (int t = 0; t < T_STEPS; ++t) {
        // prefetch next x tile + next w_lin slice (hidden under compute)
        f32x2 xv = {0.f, 0.f};
        float wl_next = 0.f;
        if (t + 1 < T_STEPS) {
            xv = *reinterpret_cast<const f32x2*>(
                &x[(size_t)(row0 + wave) * T_STEPS * 128 + (size_t)(t + 1) * 128 + (size_t)lane * 2]);
            wl_next = w_lin[(t + 1) * 128 + hid];
        }

        // A-fragments: rows = c16, k = kt*32 + kq*8 + j
        short8 af[8];
#pragma unroll
        for (int kt = 0; kt < 4; ++kt) {
            int idx = (c16 * 128 + kt * 32 + kq * 8) ^ ((c16 & 7) << 3);
            af[kt]     = *reinterpret_cast<const short8*>(&xbuf[t & 1][idx]);
            af[kt + 4] = *reinterpret_cast<const short8*>(&hbuf[idx]);
        }

        f32x4 acc[4];
#pragma unroll
        for (int n = 0; n < 4; ++n)
            acc[n] = (f32x4){bias[n], bias[n], bias[n], bias[n]};
#pragma unroll
        for (int kt = 0; kt < 8; ++kt) {
#pragma unroll
            for (int n = 0; n < 4; ++n)
                acc[n] = __builtin_amdgcn_mfma_f32_16x16x32_bf16(af[kt], bq[kt][n], acc[n], 0, 0, 0);
        }

        // elementwise: lane owns (row = kq*4+r, hid); rows>=8 are confined garbage
        float hval[4];
#pragma unroll
        for (int r = 0; r < 4; ++r) {
            float gi = acc[0][r], gf = acc[1][r], gg = acc[2][r], go = acc[3][r];
            float c = sigm(gf) * cstate[r] + sigm(gi) * tanh_fast(gg);
            cstate[r] = c;
            float h = sigm(go) * tanh_fast(c);
            hval[r] = h;
            accout[r] += h * wl_cur;
        }

        __syncthreads();  // all A-frag reads complete before overwriting LDS

#pragma unroll
        for (int r = 0; r < 4; ++r) {
            int row = kq * 4 + r;
            int idx = (row * 128 + hid) ^ ((row & 7) << 3);
            hbuf[idx] = f2bf(hval[r]);
        }
        if (t + 1 < T_STEPS) {
            unsigned int pk = (unsigned int)f2bf(xv[0]) | ((unsigned int)f2bf(xv[1]) << 16);
            int idx = (wave * 128 + lane * 2) ^ ((wave & 7) << 3);
            *reinterpret_cast<unsigned int*>(&xbuf[(t + 1) & 1][idx]) = pk;
        }
        wl_cur = wl_next;
        __syncthreads();  // writes visible before next step's MFMA reads
    }

    // ---- reduce out-acc: sum over 16-lane group (16 hidden), then waves ----
#pragma unroll
    for (int r = 0; r < 4; ++r) {
        float v = accout[r];
        v += __shfl_xor(v, 1);
        v += __shfl_xor(v, 2);
        v += __shfl_xor(v, 4);
        v += __shfl_xor(v, 8);
        if (c16 == 0 && kq < 2) redout[wave][kq * 4 + r] = v;  // rows 0..7
    }
    __syncthreads();
    if (tid < 8) {
        float s = b_lin[0];
#pragma unroll
        for (int w = 0; w < 8; ++w) s += redout[w][tid];
        out[row0 + tid] = s;
    }
}

extern "C" void kernel_launch(void* const* d_in, const int* in_sizes, int n_in,
                              void* d_out, int out_size, void* d_ws, size_t ws_size,
                              hipStream_t stream) {
    const float* x     = (const float*)d_in[0];
    const float* w_ih  = (const float*)d_in[1];
    const float* w_hh  = (const float*)d_in[2];
    const float* b_ih  = (const float*)d_in[3];
    const float* b_hh  = (const float*)d_in[4];
    const float* w_lin = (const float*)d_in[5];
    const float* b_lin = (const float*)d_in[6];
    float* out = (float*)d_out;

    lstm_fused_kernel<<<256, 512, 0, stream>>>(x, w_ih, w_hh, b_ih, b_hh, w_lin, b_lin, out);
}

// Round 2
// 275.009 us; speedup vs baseline: 1.2153x; 1.2153x over previous
//
#include <hip/hip_runtime.h>

// BiLSTM_2491081031886: LSTM(B=2048,T=256,F=H=128) + linear head, fused.
// One persistent block per CU; 8 batch rows/block staged at MFMA A-rows
// {0,1,4,5,8,9,12,13} so every lane's D-rows r=0,1 are real (no garbage
// transcendentals). Weights in registers as bf16 B-frags; x/h double-buffered
// in swizzled LDS; ONE barrier per step; out accumulated online.

typedef __attribute__((ext_vector_type(8))) short short8;
typedef __attribute__((ext_vector_type(4))) float f32x4;
typedef __attribute__((ext_vector_type(2))) float f32x2;
typedef __attribute__((ext_vector_type(2))) unsigned long long u64x2;

#define T_STEPS 256
#define L2E 1.4426950408889634f

__device__ __forceinline__ unsigned short f2bf(float f) {
    unsigned int u = __builtin_bit_cast(unsigned int, f);
    u += 0x7fffu + ((u >> 16) & 1u);   // RNE
    return (unsigned short)(u >> 16);
}
__device__ __forceinline__ float rcp_fast(float x) { return __builtin_amdgcn_rcpf(x); }
__device__ __forceinline__ float exp2f_fast(float x) { return __builtin_amdgcn_exp2f(x); }

__device__ __forceinline__ short8 pack8(const f32x4 a, const f32x4 b) {
    short8 v;
    v[0] = (short)f2bf(a[0]); v[1] = (short)f2bf(a[1]);
    v[2] = (short)f2bf(a[2]); v[3] = (short)f2bf(a[3]);
    v[4] = (short)f2bf(b[0]); v[5] = (short)f2bf(b[1]);
    v[6] = (short)f2bf(b[2]); v[7] = (short)f2bf(b[3]);
    return v;
}

__global__ __launch_bounds__(512, 2) void lstm_fused_kernel(
    const float* __restrict__ x,     // [2048,256,128]
    const float* __restrict__ w_ih,  // [512,128]
    const float* __restrict__ w_hh,  // [512,128]
    const float* __restrict__ b_ih,  // [512]
    const float* __restrict__ b_hh,  // [512]
    const float* __restrict__ w_lin, // [1, 256*128]
    const float* __restrict__ b_lin, // [1]
    float* __restrict__ out)         // [2048]
{
    // bf16 [16 rows][128 k], XOR-swizzled: ushort idx ^= (row&7)<<3
    __shared__ __align__(16) unsigned short xbuf[2][16 * 128];
    __shared__ __align__(16) unsigned short hbuf[2][16 * 128];
    __shared__ float redout[8][8];

    const int tid  = threadIdx.x;
    const int wave = tid >> 6;      // 0..7
    const int lane = tid & 63;
    const int c16  = lane & 15;
    const int kq   = lane >> 4;     // 0..3
    const int row0 = blockIdx.x * 8;
    const int hid  = wave * 16 + c16;

    // zero all x/h LDS (garbage A-rows must be 0 forever): 512 thr x 32B = 16KB
    reinterpret_cast<u64x2*>(xbuf)[tid] = (u64x2){0ull, 0ull};
    reinterpret_cast<u64x2*>(hbuf)[tid] = (u64x2){0ull, 0ull};

    // ---- weights -> register B-fragments (bf16) ----
    // wave w, gate tile n, col c16: logical gate G = n*128 + w*16 + c16
    // K: kt<4 -> w_ih, kt>=4 -> w_hh
    short8 bq[8][4];
#pragma unroll
    for (int kt = 0; kt < 8; ++kt) {
#pragma unroll
        for (int n = 0; n < 4; ++n) {
            const int G  = n * 128 + wave * 16 + c16;
            const int k0 = kt * 32 + kq * 8;
            const float* src = (kt < 4) ? (w_ih + G * 128 + k0)
                                        : (w_hh + G * 128 + (k0 - 128));
            f32x4 lo = *reinterpret_cast<const f32x4*>(src);
            f32x4 hi = *reinterpret_cast<const f32x4*>(src + 4);
            bq[kt][n] = pack8(lo, hi);
        }
    }
    float bias[4];
#pragma unroll
    for (int n = 0; n < 4; ++n) {
        const int G = n * 128 + wave * 16 + c16;
        bias[n] = b_ih[G] + b_hh[G];
    }

    __syncthreads();  // zeros visible before t=0 staging

    // batch row br=wave is staged at A-row ar = ((br>>1)<<2)|(br&1)
    const int ar    = ((wave >> 1) << 2) | (wave & 1);
    const int xwidx = (ar * 128 + lane * 2) ^ ((ar & 7) << 3);  // loop-invariant
    const float* xrow = x + (size_t)(row0 + wave) * T_STEPS * 128 + lane * 2;

    {
        f32x2 xv = *reinterpret_cast<const f32x2*>(xrow);
        unsigned int pk = (unsigned int)f2bf(xv[0]) | ((unsigned int)f2bf(xv[1]) << 16);
        *reinterpret_cast<unsigned int*>(&xbuf[0][xwidx]) = pk;
    }

    // lane (c16,kq) owns batch rows {2kq, 2kq+1} (A-rows {4kq, 4kq+1}), col hid
    float cstate[2] = {0.f, 0.f};
    float accout[2] = {0.f, 0.f};
    float wl_cur = w_lin[hid];
    const int hwidx0 = ((4 * kq + 0) * 128 + hid) ^ (((4 * kq + 0) & 7) << 3);
    const int hwidx1 = ((4 * kq + 1) * 128 + hid) ^ (((4 * kq + 1) & 7) << 3);
    __syncthreads();

    for (int t = 0; t < T_STEPS; ++t) {
        const int cur = t & 1, nxt = cur ^ 1;

        // prefetch next x tile + next w_lin slice
        f32x2 xv = {0.f, 0.f};
        float wl_next = 0.f;
        if (t + 1 < T_STEPS) {
            xv = *reinterpret_cast<const f32x2*>(xrow + (size_t)(t + 1) * 128);
            wl_next = w_lin[(t + 1) * 128 + hid];
        }

        // A-fragments: row c16, k = kt*32 + kq*8 + j
        short8 af[8];
#pragma unroll
        for (int kt = 0; kt < 4; ++kt) {
            int idx = (c16 * 128 + kt * 32 + kq * 8) ^ ((c16 & 7) << 3);
            af[kt]     = *reinterpret_cast<const short8*>(&xbuf[cur][idx]);
            af[kt + 4] = *reinterpret_cast<const short8*>(&hbuf[cur][idx]);
        }

        f32x4 acc[4];
#pragma unroll
        for (int n = 0; n < 4; ++n)
            acc[n] = (f32x4){bias[n], bias[n], bias[n], bias[n]};
#pragma unroll
        for (int kt = 0; kt < 8; ++kt) {
#pragma unroll
            for (int n = 0; n < 4; ++n)
                acc[n] = __builtin_amdgcn_mfma_f32_16x16x32_bf16(af[kt], bq[kt][n], acc[n], 0, 0, 0);
        }

        // elementwise: only r=0,1 are real rows. 5 exp + 3 rcp per element.
        unsigned short hu[2];
#pragma unroll
        for (int r = 0; r < 2; ++r) {
            float gi = acc[0][r], gf = acc[1][r], gg = acc[2][r], go = acc[3][r];
            float ef = exp2f_fast(gf * L2E);
            float ei = exp2f_fast(gi * L2E);
            float eg = exp2f_fast(gg * (2.f * L2E));
            float sf = ef * rcp_fast(ef + 1.f);
            float it = (ei * (eg - 1.f)) * rcp_fast((ei + 1.f) * (eg + 1.f));
            float c  = __builtin_fmaf(sf, cstate[r], it);
            cstate[r] = c;
            float cc = fminf(fmaxf(c, -15.f), 15.f);   // med3; keeps e^{2cc} finite
            float eo = exp2f_fast(go * L2E);
            float ec = exp2f_fast(cc * (2.f * L2E));
            float oh = (eo * (ec - 1.f)) * rcp_fast((eo + 1.f) * (ec + 1.f));
            accout[r] = __builtin_fmaf(oh, wl_cur, accout[r]);
            hu[r] = f2bf(oh);
        }

        // write next-step state into the OTHER buffers (no read-hazard:
        // readers of [nxt] drained at the barrier ending step t-1)
        hbuf[nxt][hwidx0] = hu[0];
        hbuf[nxt][hwidx1] = hu[1];
        if (t + 1 < T_STEPS) {
            unsigned int pk = (unsigned int)f2bf(xv[0]) | ((unsigned int)f2bf(xv[1]) << 16);
            *reinterpret_cast<unsigned int*>(&xbuf[nxt][xwidx]) = pk;
        }
        wl_cur = wl_next;
        __syncthreads();  // writes visible; also orders next step's overwrites
    }

    // ---- reduce accout over hid: 16-lane tree, then across waves ----
#pragma unroll
    for (int r = 0; r < 2; ++r) {
        float v = accout[r];
        v += __shfl_xor(v, 1);
        v += __shfl_xor(v, 2);
        v += __shfl_xor(v, 4);
        v += __shfl_xor(v, 8);
        if (c16 == 0) redout[wave][2 * kq + r] = v;  // batch row 2kq+r
    }
    __syncthreads();
    if (tid < 8) {
        float s = b_lin[0];
#pragma unroll
        for (int w = 0; w < 8; ++w) s += redout[w][tid];
        out[row0 + tid] = s;
    }
}

extern "C" void kernel_launch(void* const* d_in, const int* in_sizes, int n_in,
                              void* d_out, int out_size, void* d_ws, size_t ws_size,
                              hipStream_t stream) {
    const float* x     = (const float*)d_in[0];
    const float* w_ih  = (const float*)d_in[1];
    const float* w_hh  = (const float*)d_in[2];
    const float* b_ih  = (const float*)d_in[3];
    const float* b_hh  = (const float*)d_in[4];
    const float* w_lin = (const float*)d_in[5];
    const float* b_lin = (const float*)d_in[6];
    float* out = (float*)d_out;

    lstm_fused_kernel<<<256, 512, 0, stream>>>(x, w_ih, w_hh, b_ih, b_hh, w_lin, b_lin, out);
}

// Round 3
// 259.634 us; speedup vs baseline: 1.2872x; 1.0592x over previous
//
#include <hip/hip_runtime.h>

// BiLSTM: LSTM(B=2048,T=256,F=H=128) + linear head, fused, one block/CU.
// Round 3: software-pipelined recurrence. x-gates for step t+1 computed
// during step t (second accumulator set), x staged 2 steps ahead via reg
// prefetch, light barrier (lgkmcnt only) so VMEM prefetch spans barriers.
// 8 batch rows at MFMA A-rows {0,1,4,5,8,9,12,13} -> every lane's D-rows
// r=0,1 real. Weights in registers (128 VGPR of bf16 B-frags).

typedef __attribute__((ext_vector_type(8))) short short8;
typedef __attribute__((ext_vector_type(4))) float f32x4;
typedef __attribute__((ext_vector_type(2))) float f32x2;
typedef __attribute__((ext_vector_type(2))) unsigned long long u64x2;

#define T_STEPS 256
#define L2E 1.4426950408889634f

__device__ __forceinline__ unsigned short f2bf(float f) {
    unsigned int u = __builtin_bit_cast(unsigned int, f);
    u += 0x7fffu + ((u >> 16) & 1u);   // RNE
    return (unsigned short)(u >> 16);
}
__device__ __forceinline__ float rcp_fast(float x) { return __builtin_amdgcn_rcpf(x); }
__device__ __forceinline__ float exp2f_fast(float x) { return __builtin_amdgcn_exp2f(x); }

__device__ __forceinline__ short8 pack8(const f32x4 a, const f32x4 b) {
    short8 v;
    v[0] = (short)f2bf(a[0]); v[1] = (short)f2bf(a[1]);
    v[2] = (short)f2bf(a[2]); v[3] = (short)f2bf(a[3]);
    v[4] = (short)f2bf(b[0]); v[5] = (short)f2bf(b[1]);
    v[6] = (short)f2bf(b[2]); v[7] = (short)f2bf(b[3]);
    return v;
}

// barrier that drains LDS ops only; VMEM prefetches stay in flight
#define LBAR() asm volatile("s_waitcnt lgkmcnt(0)\n\ts_barrier" ::: "memory")

// One LSTM step. T = timestep, CUR = T&1 (literal), GC = gates for step T
// (already holds bias + x[T]*w_ih), GN = accumulator to fill with
// bias + x[T+1]*w_ih for the next step.
#define STEP(T, CUR, GC, GN)                                                   \
  do {                                                                         \
    const int nxt_ = (CUR) ^ 1;                                                \
    short8 afh[4], afx[4];                                                     \
    _Pragma("unroll")                                                          \
    for (int kt = 0; kt < 4; ++kt) {                                           \
      int idx = (c16 * 128 + kt * 32 + kq * 8) ^ ((c16 & 7) << 3);             \
      afh[kt] = *reinterpret_cast<const short8*>(&hbuf[(CUR)][idx]);           \
    }                                                                          \
    _Pragma("unroll")                                                          \
    for (int kt = 0; kt < 4; ++kt) {                                           \
      int idx = (c16 * 128 + kt * 32 + kq * 8) ^ ((c16 & 7) << 3);             \
      afx[kt] = *reinterpret_cast<const short8*>(&xbuf[nxt_][idx]);            \
    }                                                                          \
    _Pragma("unroll")                                                          \
    for (int kt = 0; kt < 4; ++kt)                                             \
      _Pragma("unroll")                                                        \
      for (int n = 0; n < 4; ++n)                                              \
        GC[n] = __builtin_amdgcn_mfma_f32_16x16x32_bf16(afh[kt], bq[kt + 4][n],\
                                                        GC[n], 0, 0, 0);       \
    _Pragma("unroll")                                                          \
    for (int n = 0; n < 4; ++n)                                                \
      GN[n] = (f32x4){bias[n], bias[n], bias[n], bias[n]};                     \
    _Pragma("unroll")                                                          \
    for (int kt = 0; kt < 4; ++kt)                                             \
      _Pragma("unroll")                                                        \
      for (int n = 0; n < 4; ++n)                                              \
        GN[n] = __builtin_amdgcn_mfma_f32_16x16x32_bf16(afx[kt], bq[kt][n],    \
                                                        GN[n], 0, 0, 0);       \
    if ((T) + 2 < T_STEPS) { /* x[T+2] (prefetched last step) -> LDS */        \
      unsigned int pk = (unsigned int)f2bf(xv_hold[0]) |                       \
                        ((unsigned int)f2bf(xv_hold[1]) << 16);                \
      *reinterpret_cast<unsigned int*>(&xbuf[(CUR)][xwidx]) = pk;              \
    }                                                                          \
    if ((T) + 3 < T_STEPS) /* issue x[T+3]; lands across the barrier */        \
      xv_hold = *reinterpret_cast<const f32x2*>(xrow + (size_t)((T) + 3) * 128);\
    unsigned short hu0, hu1;                                                   \
    _Pragma("unroll")                                                          \
    for (int r = 0; r < 2; ++r) {                                              \
      float gi = GC[0][r], gf = GC[1][r], gg = GC[2][r], go = GC[3][r];        \
      float ef = exp2f_fast(gf * L2E);                                         \
      float ei = exp2f_fast(gi * L2E);                                         \
      float eg = exp2f_fast(gg * (2.f * L2E));                                 \
      float sf = ef * rcp_fast(ef + 1.f);                                      \
      float it = (ei * (eg - 1.f)) * rcp_fast((ei + 1.f) * (eg + 1.f));        \
      float c  = __builtin_fmaf(sf, cstate[r], it);                            \
      cstate[r] = c;                                                           \
      float cc = fminf(fmaxf(c, -15.f), 15.f);                                 \
      float eo = exp2f_fast(go * L2E);                                         \
      float ec = exp2f_fast(cc * (2.f * L2E));                                 \
      float oh = (eo * (ec - 1.f)) * rcp_fast((eo + 1.f) * (ec + 1.f));        \
      accout[r] = __builtin_fmaf(oh, wl_cur, accout[r]);                       \
      if (r == 0) hu0 = f2bf(oh); else hu1 = f2bf(oh);                         \
    }                                                                          \
    hbuf[nxt_][hwidx0] = hu0;                                                  \
    hbuf[nxt_][hwidx1] = hu1;                                                  \
    wl_cur = wl_next;                                                          \
    if ((T) + 2 < T_STEPS) wl_next = w_lin[((T) + 2) * 128 + hid];             \
    LBAR();                                                                    \
  } while (0)

__global__ __launch_bounds__(512, 2) void lstm_fused_kernel(
    const float* __restrict__ x,     // [2048,256,128]
    const float* __restrict__ w_ih,  // [512,128]
    const float* __restrict__ w_hh,  // [512,128]
    const float* __restrict__ b_ih,  // [512]
    const float* __restrict__ b_hh,  // [512]
    const float* __restrict__ w_lin, // [1, 256*128]
    const float* __restrict__ b_lin, // [1]
    float* __restrict__ out)         // [2048]
{
    // bf16 [16 rows][128 k], XOR-swizzled: ushort idx ^= (row&7)<<3
    __shared__ __align__(16) unsigned short xbuf[2][16 * 128];
    __shared__ __align__(16) unsigned short hbuf[2][16 * 128];
    __shared__ float redout[8][8];

    const int tid  = threadIdx.x;
    const int wave = tid >> 6;      // 0..7
    const int lane = tid & 63;
    const int c16  = lane & 15;
    const int kq   = lane >> 4;     // 0..3
    const int row0 = blockIdx.x * 8;
    const int hid  = wave * 16 + c16;

    // zero x/h LDS (garbage A-rows must stay 0): 512 thr x 32B = 16KB
    reinterpret_cast<u64x2*>(xbuf)[tid] = (u64x2){0ull, 0ull};
    reinterpret_cast<u64x2*>(hbuf)[tid] = (u64x2){0ull, 0ull};

    // ---- weights -> register B-fragments (bf16) ----
    short8 bq[8][4];
#pragma unroll
    for (int kt = 0; kt < 8; ++kt) {
#pragma unroll
        for (int n = 0; n < 4; ++n) {
            const int G  = n * 128 + wave * 16 + c16;
            const int k0 = kt * 32 + kq * 8;
            const float* src = (kt < 4) ? (w_ih + G * 128 + k0)
                                        : (w_hh + G * 128 + (k0 - 128));
            f32x4 lo = *reinterpret_cast<const f32x4*>(src);
            f32x4 hi = *reinterpret_cast<const f32x4*>(src + 4);
            bq[kt][n] = pack8(lo, hi);
        }
    }
    float bias[4];
#pragma unroll
    for (int n = 0; n < 4; ++n) {
        const int G = n * 128 + wave * 16 + c16;
        bias[n] = b_ih[G] + b_hh[G];
    }

    __syncthreads();  // zeros visible

    // batch row br=wave staged at A-row ar = ((br>>1)<<2)|(br&1)
    const int ar    = ((wave >> 1) << 2) | (wave & 1);
    const int xwidx = (ar * 128 + lane * 2) ^ ((ar & 7) << 3);
    const float* xrow = x + (size_t)(row0 + wave) * T_STEPS * 128 + lane * 2;

    // prologue: stage x[0]->xbuf[0], x[1]->xbuf[1]
    {
        f32x2 v0 = *reinterpret_cast<const f32x2*>(xrow);
        f32x2 v1 = *reinterpret_cast<const f32x2*>(xrow + 128);
        unsigned int p0 = (unsigned int)f2bf(v0[0]) | ((unsigned int)f2bf(v0[1]) << 16);
        unsigned int p1 = (unsigned int)f2bf(v1[0]) | ((unsigned int)f2bf(v1[1]) << 16);
        *reinterpret_cast<unsigned int*>(&xbuf[0][xwidx]) = p0;
        *reinterpret_cast<unsigned int*>(&xbuf[1][xwidx]) = p1;
    }
    __syncthreads();

    // gA = bias + x[0]*w_ih
    f32x4 gA[4], gB[4];
    {
        short8 afx[4];
#pragma unroll
        for (int kt = 0; kt < 4; ++kt) {
            int idx = (c16 * 128 + kt * 32 + kq * 8) ^ ((c16 & 7) << 3);
            afx[kt] = *reinterpret_cast<const short8*>(&xbuf[0][idx]);
        }
#pragma unroll
        for (int n = 0; n < 4; ++n)
            gA[n] = (f32x4){bias[n], bias[n], bias[n], bias[n]};
#pragma unroll
        for (int kt = 0; kt < 4; ++kt)
#pragma unroll
            for (int n = 0; n < 4; ++n)
                gA[n] = __builtin_amdgcn_mfma_f32_16x16x32_bf16(afx[kt], bq[kt][n], gA[n], 0, 0, 0);
    }

    f32x2 xv_hold = *reinterpret_cast<const f32x2*>(xrow + 2 * 128);  // x[2]
    float wl_cur  = w_lin[hid];
    float wl_next = w_lin[128 + hid];
    float cstate[2] = {0.f, 0.f};
    float accout[2] = {0.f, 0.f};
    const int hwidx0 = ((4 * kq + 0) * 128 + hid) ^ (((4 * kq + 0) & 7) << 3);
    const int hwidx1 = ((4 * kq + 1) * 128 + hid) ^ (((4 * kq + 1) & 7) << 3);

    __syncthreads();  // all prologue xbuf[0] reads done before t=0 overwrites it

    for (int t = 0; t < T_STEPS; t += 2) {
        STEP(t,     0, gA, gB);
        STEP(t + 1, 1, gB, gA);
    }

    // ---- reduce accout over hid: 16-lane tree, then across waves ----
#pragma unroll
    for (int r = 0; r < 2; ++r) {
        float v = accout[r];
        v += __shfl_xor(v, 1);
        v += __shfl_xor(v, 2);
        v += __shfl_xor(v, 4);
        v += __shfl_xor(v, 8);
        if (c16 == 0) redout[wave][2 * kq + r] = v;  // batch row 2kq+r
    }
    __syncthreads();
    if (tid < 8) {
        float s = b_lin[0];
#pragma unroll
        for (int w = 0; w < 8; ++w) s += redout[w][tid];
        out[row0 + tid] = s;
    }
}

extern "C" void kernel_launch(void* const* d_in, const int* in_sizes, int n_in,
                              void* d_out, int out_size, void* d_ws, size_t ws_size,
                              hipStream_t stream) {
    const float* x     = (const float*)d_in[0];
    const float* w_ih  = (const float*)d_in[1];
    const float* w_hh  = (const float*)d_in[2];
    const float* b_ih  = (const float*)d_in[3];
    const float* b_hh  = (const float*)d_in[4];
    const float* w_lin = (const float*)d_in[5];
    const float* b_lin = (const float*)d_in[6];
    float* out = (float*)d_out;

    lstm_fused_kernel<<<256, 512, 0, stream>>>(x, w_ih, w_hh, b_ih, b_hh, w_lin, b_lin, out);
}

// Round 4
// 218.871 us; speedup vs baseline: 1.5270x; 1.1862x over previous
//
#include <hip/hip_runtime.h>

// BiLSTM: LSTM(B=2048,T=256,F=H=128) + linear head, fused, one block/CU.
// Round 4: x-matmul batched over 2 timesteps (all 16 MFMA M-rows real:
// A-row 4kq+j+2s holds x[batch 2kq+j][t0+s]); h-MFMA split into two 2-deep
// accumulate chains; v_cvt_pk_bf16_f32 for bf16 packing; light barriers.

typedef __attribute__((ext_vector_type(8))) short short8;
typedef __attribute__((ext_vector_type(4))) float f32x4;
typedef __attribute__((ext_vector_type(2))) float f32x2;
typedef __attribute__((ext_vector_type(2))) unsigned long long u64x2;

#define T_STEPS 256
#define L2E 1.4426950408889634f

__device__ __forceinline__ unsigned int cvt_pk_bf16(float lo, float hi) {
    unsigned int r;
    asm volatile("v_cvt_pk_bf16_f32 %0, %1, %2" : "=v"(r) : "v"(lo), "v"(hi));
    return r;
}
__device__ __forceinline__ unsigned short f2bf(float f) {
    unsigned int u = __builtin_bit_cast(unsigned int, f);
    u += 0x7fffu + ((u >> 16) & 1u);   // RNE
    return (unsigned short)(u >> 16);
}
__device__ __forceinline__ float rcp_fast(float x) { return __builtin_amdgcn_rcpf(x); }
__device__ __forceinline__ float exp2f_fast(float x) { return __builtin_amdgcn_exp2f(x); }

__device__ __forceinline__ short8 pack8(const f32x4 a, const f32x4 b) {
    short8 v;
    v[0] = (short)f2bf(a[0]); v[1] = (short)f2bf(a[1]);
    v[2] = (short)f2bf(a[2]); v[3] = (short)f2bf(a[3]);
    v[4] = (short)f2bf(b[0]); v[5] = (short)f2bf(b[1]);
    v[6] = (short)f2bf(b[2]); v[7] = (short)f2bf(b[3]);
    return v;
}

// barrier that drains LDS ops only; VMEM prefetches stay in flight
#define LBAR() asm volatile("s_waitcnt lgkmcnt(0)\n\ts_barrier" ::: "memory")

// elementwise for sub-step S (0/1): gates = gX[][2S+j] + gh0[][j] + gh1[][j];
// writes h into hbuf[WR]
#define ELEM(S, WL, WR)                                                        \
  do {                                                                         \
    float oh0_ = 0.f, oh1_ = 0.f;                                              \
    _Pragma("unroll")                                                          \
    for (int j = 0; j < 2; ++j) {                                              \
      float gi = gX[0][2*(S)+j] + gh0[0][j] + gh1[0][j];                       \
      float gf = gX[1][2*(S)+j] + gh0[1][j] + gh1[1][j];                       \
      float gg = gX[2][2*(S)+j] + gh0[2][j] + gh1[2][j];                       \
      float go = gX[3][2*(S)+j] + gh0[3][j] + gh1[3][j];                       \
      float ef = exp2f_fast(gf * L2E);                                         \
      float ei = exp2f_fast(gi * L2E);                                         \
      float eg = exp2f_fast(gg * (2.f * L2E));                                 \
      float sf = ef * rcp_fast(ef + 1.f);                                      \
      float it = (ei * (eg - 1.f)) * rcp_fast((ei + 1.f) * (eg + 1.f));        \
      float c  = __builtin_fmaf(sf, cstate[j], it);                            \
      cstate[j] = c;                                                           \
      float cc = fminf(fmaxf(c, -15.f), 15.f);                                 \
      float eo = exp2f_fast(go * L2E);                                         \
      float ec = exp2f_fast(cc * (2.f * L2E));                                 \
      float oh = (eo * (ec - 1.f)) * rcp_fast((eo + 1.f) * (ec + 1.f));        \
      accout[j] = __builtin_fmaf(oh, (WL), accout[j]);                         \
      if (j == 0) oh0_ = oh; else oh1_ = oh;                                   \
    }                                                                          \
    unsigned int pk_ = cvt_pk_bf16(oh0_, oh1_);                                \
    hbuf[WR][hwidx0] = (unsigned short)pk_;                                    \
    hbuf[WR][hwidx1] = (unsigned short)(pk_ >> 16);                            \
  } while (0)

// one 2-step group starting at even T0; XP = xbuf parity of this group
#define GROUP(T0, XP)                                                          \
  do {                                                                         \
    short8 afh[4], afx[4];                                                     \
    _Pragma("unroll")                                                          \
    for (int kt = 0; kt < 4; ++kt) {                                           \
      int idx = (c16 * 128 + kt * 32 + kq * 8) ^ ((c16 & 7) << 3);             \
      afh[kt] = *reinterpret_cast<const short8*>(&hbuf[0][idx]);               \
      afx[kt] = *reinterpret_cast<const short8*>(&xbuf[XP][idx]);              \
    }                                                                          \
    /* prefetch next group's x + w_lin (consumed in step B / next group) */    \
    {                                                                          \
      const int tt = ((T0) + 2 < T_STEPS) ? (T0) + 2 : 0;                      \
      nx0 = *reinterpret_cast<const f32x2*>(xrow + (size_t)tt * 128);          \
      nx1 = *reinterpret_cast<const f32x2*>(xrow + (size_t)(tt + 1) * 128);    \
      wlA2 = w_lin[tt * 128 + hid];                                            \
      wlB2 = w_lin[(tt + 1) * 128 + hid];                                      \
    }                                                                          \
    f32x4 gX[4], gh0[4], gh1[4];                                               \
    _Pragma("unroll")                                                          \
    for (int n = 0; n < 4; ++n) {                                              \
      gX[n] = (f32x4){bias[n], bias[n], bias[n], bias[n]};                     \
      gh0[n] = (f32x4){0.f, 0.f, 0.f, 0.f};                                    \
      gh1[n] = (f32x4){0.f, 0.f, 0.f, 0.f};                                    \
    }                                                                          \
    _Pragma("unroll")                                                          \
    for (int n = 0; n < 4; ++n) {                                              \
      gh0[n] = __builtin_amdgcn_mfma_f32_16x16x32_bf16(afh[0], bq[4][n], gh0[n], 0, 0, 0); \
      gh1[n] = __builtin_amdgcn_mfma_f32_16x16x32_bf16(afh[2], bq[6][n], gh1[n], 0, 0, 0); \
    }                                                                          \
    _Pragma("unroll")                                                          \
    for (int n = 0; n < 4; ++n) {                                              \
      gh0[n] = __builtin_amdgcn_mfma_f32_16x16x32_bf16(afh[1], bq[5][n], gh0[n], 0, 0, 0); \
      gh1[n] = __builtin_amdgcn_mfma_f32_16x16x32_bf16(afh[3], bq[7][n], gh1[n], 0, 0, 0); \
    }                                                                          \
    _Pragma("unroll")                                                          \
    for (int kt = 0; kt < 4; ++kt)                                             \
      _Pragma("unroll")                                                        \
      for (int n = 0; n < 4; ++n)                                              \
        gX[n] = __builtin_amdgcn_mfma_f32_16x16x32_bf16(afx[kt], bq[kt][n], gX[n], 0, 0, 0); \
    ELEM(0, wlA, 1);                                                           \
    LBAR();                                                                    \
    /* ---- step B (s=1) ---- */                                               \
    _Pragma("unroll")                                                          \
    for (int kt = 0; kt < 4; ++kt) {                                           \
      int idx = (c16 * 128 + kt * 32 + kq * 8) ^ ((c16 & 7) << 3);             \
      afh[kt] = *reinterpret_cast<const short8*>(&hbuf[1][idx]);               \
    }                                                                          \
    _Pragma("unroll")                                                          \
    for (int n = 0; n < 4; ++n) {                                              \
      gh0[n] = (f32x4){0.f, 0.f, 0.f, 0.f};                                    \
      gh1[n] = (f32x4){0.f, 0.f, 0.f, 0.f};                                    \
    }                                                                          \
    _Pragma("unroll")                                                          \
    for (int n = 0; n < 4; ++n) {                                              \
      gh0[n] = __builtin_amdgcn_mfma_f32_16x16x32_bf16(afh[0], bq[4][n], gh0[n], 0, 0, 0); \
      gh1[n] = __builtin_amdgcn_mfma_f32_16x16x32_bf16(afh[2], bq[6][n], gh1[n], 0, 0, 0); \
    }                                                                          \
    _Pragma("unroll")                                                          \
    for (int n = 0; n < 4; ++n) {                                              \
      gh0[n] = __builtin_amdgcn_mfma_f32_16x16x32_bf16(afh[1], bq[5][n], gh0[n], 0, 0, 0); \
      gh1[n] = __builtin_amdgcn_mfma_f32_16x16x32_bf16(afh[3], bq[7][n], gh1[n], 0, 0, 0); \
    }                                                                          \
    /* stage next group's x into the other xbuf */                             \
    {                                                                          \
      unsigned int p0 = cvt_pk_bf16(nx0[0], nx0[1]);                           \
      unsigned int p1 = cvt_pk_bf16(nx1[0], nx1[1]);                           \
      *reinterpret_cast<unsigned int*>(&xbuf[(XP) ^ 1][xwidx0]) = p0;          \
      *reinterpret_cast<unsigned int*>(&xbuf[(XP) ^ 1][xwidx1]) = p1;          \
    }                                                                          \
    ELEM(1, wlB, 0);                                                           \
    wlA = wlA2; wlB = wlB2;                                                    \
    LBAR();                                                                    \
  } while (0)

__global__ __launch_bounds__(512, 2) void lstm_fused_kernel(
    const float* __restrict__ x,     // [2048,256,128]
    const float* __restrict__ w_ih,  // [512,128]
    const float* __restrict__ w_hh,  // [512,128]
    const float* __restrict__ b_ih,  // [512]
    const float* __restrict__ b_hh,  // [512]
    const float* __restrict__ w_lin, // [1, 256*128]
    const float* __restrict__ b_lin, // [1]
    float* __restrict__ out)         // [2048]
{
    // bf16 [16 rows][128 k], XOR-swizzled: ushort idx ^= (row&7)<<3
    __shared__ __align__(16) unsigned short xbuf[2][16 * 128];
    __shared__ __align__(16) unsigned short hbuf[2][16 * 128];
    __shared__ float redout[8][8];

    const int tid  = threadIdx.x;
    const int wave = tid >> 6;      // 0..7
    const int lane = tid & 63;
    const int c16  = lane & 15;
    const int kq   = lane >> 4;     // 0..3
    const int row0 = blockIdx.x * 8;
    const int hid  = wave * 16 + c16;

    // zero hbuf (rows == 2,3 mod 4 must stay 0 forever): 2*4KB = 8KB
    reinterpret_cast<u64x2*>(hbuf)[tid] = (u64x2){0ull, 0ull};

    // ---- weights -> register B-fragments (bf16) ----
    // wave w, gate tile n, col c16: logical gate G = n*128 + w*16 + c16
    // K: kt<4 -> w_ih, kt>=4 -> w_hh
    short8 bq[8][4];
#pragma unroll
    for (int kt = 0; kt < 8; ++kt) {
#pragma unroll
        for (int n = 0; n < 4; ++n) {
            const int G  = n * 128 + wave * 16 + c16;
            const int k0 = kt * 32 + kq * 8;
            const float* src = (kt < 4) ? (w_ih + G * 128 + k0)
                                        : (w_hh + G * 128 + (k0 - 128));
            f32x4 lo = *reinterpret_cast<const f32x4*>(src);
            f32x4 hi = *reinterpret_cast<const f32x4*>(src + 4);
            bq[kt][n] = pack8(lo, hi);
        }
    }
    float bias[4];
#pragma unroll
    for (int n = 0; n < 4; ++n) {
        const int G = n * 128 + wave * 16 + c16;
        bias[n] = b_ih[G] + b_hh[G];
    }

    // x staging: wave w owns batch row b=w; step-parity s goes to
    // A-row r0 + 2s where r0 = 4*(w>>1) + (w&1)
    const int r0s    = 4 * (wave >> 1) + (wave & 1);
    const int r1s    = r0s + 2;
    const int xwidx0 = (r0s * 128 + lane * 2) ^ ((r0s & 7) << 3);
    const int xwidx1 = (r1s * 128 + lane * 2) ^ ((r1s & 7) << 3);
    const float* xrow = x + (size_t)(row0 + wave) * T_STEPS * 128 + lane * 2;

    // prologue: stage steps 0,1 into xbuf[0]
    {
        f32x2 v0 = *reinterpret_cast<const f32x2*>(xrow);
        f32x2 v1 = *reinterpret_cast<const f32x2*>(xrow + 128);
        unsigned int p0 = cvt_pk_bf16(v0[0], v0[1]);
        unsigned int p1 = cvt_pk_bf16(v1[0], v1[1]);
        *reinterpret_cast<unsigned int*>(&xbuf[0][xwidx0]) = p0;
        *reinterpret_cast<unsigned int*>(&xbuf[0][xwidx1]) = p1;
    }

    // lane (c16,kq) owns batch rows {2kq+j}, j=0,1; h lives at A-row 4kq+j
    float cstate[2] = {0.f, 0.f};
    float accout[2] = {0.f, 0.f};
    float wlA = w_lin[hid];
    float wlB = w_lin[128 + hid];
    float wlA2, wlB2;
    f32x2 nx0, nx1;
    const int hwidx0 = ((4 * kq + 0) * 128 + hid) ^ (((4 * kq + 0) & 7) << 3);
    const int hwidx1 = ((4 * kq + 1) * 128 + hid) ^ (((4 * kq + 1) & 7) << 3);

    __syncthreads();  // zeros + x[0..1] staged

    for (int t = 0; t < T_STEPS; t += 4) {
        GROUP(t, 0);
        GROUP(t + 2, 1);
    }

    // ---- reduce accout over hid: 16-lane tree, then across waves ----
#pragma unroll
    for (int r = 0; r < 2; ++r) {
        float v = accout[r];
        v += __shfl_xor(v, 1);
        v += __shfl_xor(v, 2);
        v += __shfl_xor(v, 4);
        v += __shfl_xor(v, 8);
        if (c16 == 0) redout[wave][2 * kq + r] = v;  // batch row 2kq+r
    }
    __syncthreads();
    if (tid < 8) {
        float s = b_lin[0];
#pragma unroll
        for (int w = 0; w < 8; ++w) s += redout[w][tid];
        out[row0 + tid] = s;
    }
}

extern "C" void kernel_launch(void* const* d_in, const int* in_sizes, int n_in,
                              void* d_out, int out_size, void* d_ws, size_t ws_size,
                              hipStream_t stream) {
    const float* x     = (const float*)d_in[0];
    const float* w_ih  = (const float*)d_in[1];
    const float* w_hh  = (const float*)d_in[2];
    const float* b_ih  = (const float*)d_in[3];
    const float* b_hh  = (const float*)d_in[4];
    const float* w_lin = (const float*)d_in[5];
    const float* b_lin = (const float*)d_in[6];
    float* out = (float*)d_out;

    lstm_fused_kernel<<<256, 512, 0, stream>>>(x, w_ih, w_hh, b_ih, b_hh, w_lin, b_lin, out);
}

// Round 5
// 197.731 us; speedup vs baseline: 1.6902x; 1.1069x over previous
//
#include <hip/hip_runtime.h>

// BiLSTM: LSTM(B=2048,T=256,F=H=128) + linear head, fused, one block/CU.
// Round 5: compact 8-row hbuf (2KB) — lane pairs (c16, c16|2) read the SAME
// address (broadcast, free) so distinct h-read traffic halves; h-writes are
// bank-conflict-free under the ^(row<<3) swizzle. Fused triple-rcp gate math
// (7 trans/element). x-matmul still batched 2 steps; light barriers.

typedef __attribute__((ext_vector_type(8))) short short8;
typedef __attribute__((ext_vector_type(4))) float f32x4;
typedef __attribute__((ext_vector_type(2))) float f32x2;
typedef __attribute__((ext_vector_type(2))) unsigned long long u64x2;

#define T_STEPS 256
#define L2E 1.4426950408889634f

__device__ __forceinline__ unsigned int cvt_pk_bf16(float lo, float hi) {
    unsigned int r;
    asm volatile("v_cvt_pk_bf16_f32 %0, %1, %2" : "=v"(r) : "v"(lo), "v"(hi));
    return r;
}
__device__ __forceinline__ unsigned short f2bf(float f) {
    unsigned int u = __builtin_bit_cast(unsigned int, f);
    u += 0x7fffu + ((u >> 16) & 1u);   // RNE
    return (unsigned short)(u >> 16);
}
__device__ __forceinline__ float rcp_fast(float x) { return __builtin_amdgcn_rcpf(x); }
__device__ __forceinline__ float exp2f_fast(float x) { return __builtin_amdgcn_exp2f(x); }

__device__ __forceinline__ short8 pack8(const f32x4 a, const f32x4 b) {
    short8 v;
    v[0] = (short)f2bf(a[0]); v[1] = (short)f2bf(a[1]);
    v[2] = (short)f2bf(a[2]); v[3] = (short)f2bf(a[3]);
    v[4] = (short)f2bf(b[0]); v[5] = (short)f2bf(b[1]);
    v[6] = (short)f2bf(b[2]); v[7] = (short)f2bf(b[3]);
    return v;
}

// barrier that drains LDS ops only; VMEM prefetches stay in flight
#define LBAR() asm volatile("s_waitcnt lgkmcnt(0)\n\ts_barrier" ::: "memory")

// elementwise for sub-step S (0/1): gates = gX[][2S+j] + gh0[][j] + gh1[][j]
// c' = [ef*I*G*c + ei*(eg-1)*F] * rcp(F*I*G)  (one rcp for sigm(f)&sigm(i)tanh(g))
#define ELEM(S, WL, WR)                                                        \
  do {                                                                         \
    float oh0_, oh1_;                                                          \
    _Pragma("unroll")                                                          \
    for (int j = 0; j < 2; ++j) {                                              \
      float gi = gX[0][2*(S)+j] + gh0[0][j] + gh1[0][j];                       \
      float gf = gX[1][2*(S)+j] + gh0[1][j] + gh1[1][j];                       \
      float gg = gX[2][2*(S)+j] + gh0[2][j] + gh1[2][j];                       \
      float go = gX[3][2*(S)+j] + gh0[3][j] + gh1[3][j];                       \
      float ef = exp2f_fast(gf * L2E);                                         \
      float ei = exp2f_fast(gi * L2E);                                         \
      float eg = exp2f_fast(gg * (2.f * L2E));                                 \
      float F = ef + 1.f, I = ei + 1.f, G = eg + 1.f;                          \
      float p  = I * G;                                                        \
      float R  = rcp_fast(F * p);                                              \
      float t1 = ef * p;                                                       \
      float t4 = (ei * F) * (eg - 1.f);                                        \
      float c  = __builtin_fmaf(t1, cstate[j], t4) * R;                        \
      cstate[j] = c;                                                           \
      float cc = fminf(fmaxf(c, -15.f), 15.f);                                 \
      float eo = exp2f_fast(go * L2E);                                         \
      float ec = exp2f_fast(cc * (2.f * L2E));                                 \
      float oh = (eo * (ec - 1.f)) * rcp_fast((eo + 1.f) * (ec + 1.f));        \
      accout[j] = __builtin_fmaf(oh, (WL), accout[j]);                         \
      if (j == 0) oh0_ = oh; else oh1_ = oh;                                   \
    }                                                                          \
    unsigned int pk_ = cvt_pk_bf16(oh0_, oh1_);                                \
    hbuf[WR][hwidx0] = (unsigned short)pk_;                                    \
    hbuf[WR][hwidx1] = (unsigned short)(pk_ >> 16);                            \
  } while (0)

// one 2-step group starting at even T0; XP = xbuf parity of this group
#define GROUP(T0, XP)                                                          \
  do {                                                                         \
    short8 afh[4], afx[4];                                                     \
    _Pragma("unroll")                                                          \
    for (int kt = 0; kt < 4; ++kt) {                                           \
      int idxh = (hcr * 128 + kt * 32 + kq * 8) ^ (hcr << 3);                  \
      afh[kt] = *reinterpret_cast<const short8*>(&hbuf[0][idxh]);              \
    }                                                                          \
    _Pragma("unroll")                                                          \
    for (int kt = 0; kt < 4; ++kt) {                                           \
      int idx = (c16 * 128 + kt * 32 + kq * 8) ^ ((c16 & 7) << 3);             \
      afx[kt] = *reinterpret_cast<const short8*>(&xbuf[XP][idx]);              \
    }                                                                          \
    /* prefetch next group's x + w_lin (consumed in step B / next group) */    \
    {                                                                          \
      const int tt = ((T0) + 2 < T_STEPS) ? (T0) + 2 : 0;                      \
      nx0 = *reinterpret_cast<const f32x2*>(xrow + (size_t)tt * 128);          \
      nx1 = *reinterpret_cast<const f32x2*>(xrow + (size_t)(tt + 1) * 128);    \
      wlA2 = w_lin[tt * 128 + hid];                                            \
      wlB2 = w_lin[(tt + 1) * 128 + hid];                                      \
    }                                                                          \
    f32x4 gX[4], gh0[4], gh1[4];                                               \
    _Pragma("unroll")                                                          \
    for (int n = 0; n < 4; ++n) {                                              \
      gX[n] = (f32x4){bias[n], bias[n], bias[n], bias[n]};                     \
      gh0[n] = (f32x4){0.f, 0.f, 0.f, 0.f};                                    \
      gh1[n] = (f32x4){0.f, 0.f, 0.f, 0.f};                                    \
    }                                                                          \
    _Pragma("unroll")                                                          \
    for (int n = 0; n < 4; ++n) {                                              \
      gh0[n] = __builtin_amdgcn_mfma_f32_16x16x32_bf16(afh[0], bq[4][n], gh0[n], 0, 0, 0); \
      gh1[n] = __builtin_amdgcn_mfma_f32_16x16x32_bf16(afh[2], bq[6][n], gh1[n], 0, 0, 0); \
    }                                                                          \
    _Pragma("unroll")                                                          \
    for (int n = 0; n < 4; ++n) {                                              \
      gh0[n] = __builtin_amdgcn_mfma_f32_16x16x32_bf16(afh[1], bq[5][n], gh0[n], 0, 0, 0); \
      gh1[n] = __builtin_amdgcn_mfma_f32_16x16x32_bf16(afh[3], bq[7][n], gh1[n], 0, 0, 0); \
    }                                                                          \
    _Pragma("unroll")                                                          \
    for (int kt = 0; kt < 4; ++kt)                                             \
      _Pragma("unroll")                                                        \
      for (int n = 0; n < 4; ++n)                                              \
        gX[n] = __builtin_amdgcn_mfma_f32_16x16x32_bf16(afx[kt], bq[kt][n], gX[n], 0, 0, 0); \
    ELEM(0, wlA, 1);                                                           \
    LBAR();                                                                    \
    /* ---- step B (s=1) ---- */                                               \
    _Pragma("unroll")                                                          \
    for (int kt = 0; kt < 4; ++kt) {                                           \
      int idxh = (hcr * 128 + kt * 32 + kq * 8) ^ (hcr << 3);                  \
      afh[kt] = *reinterpret_cast<const short8*>(&hbuf[1][idxh]);              \
    }                                                                          \
    _Pragma("unroll")                                                          \
    for (int n = 0; n < 4; ++n) {                                              \
      gh0[n] = (f32x4){0.f, 0.f, 0.f, 0.f};                                    \
      gh1[n] = (f32x4){0.f, 0.f, 0.f, 0.f};                                    \
    }                                                                          \
    _Pragma("unroll")                                                          \
    for (int n = 0; n < 4; ++n) {                                              \
      gh0[n] = __builtin_amdgcn_mfma_f32_16x16x32_bf16(afh[0], bq[4][n], gh0[n], 0, 0, 0); \
      gh1[n] = __builtin_amdgcn_mfma_f32_16x16x32_bf16(afh[2], bq[6][n], gh1[n], 0, 0, 0); \
    }                                                                          \
    _Pragma("unroll")                                                          \
    for (int n = 0; n < 4; ++n) {                                              \
      gh0[n] = __builtin_amdgcn_mfma_f32_16x16x32_bf16(afh[1], bq[5][n], gh0[n], 0, 0, 0); \
      gh1[n] = __builtin_amdgcn_mfma_f32_16x16x32_bf16(afh[3], bq[7][n], gh1[n], 0, 0, 0); \
    }                                                                          \
    /* stage next group's x into the other xbuf */                             \
    {                                                                          \
      unsigned int p0 = cvt_pk_bf16(nx0[0], nx0[1]);                           \
      unsigned int p1 = cvt_pk_bf16(nx1[0], nx1[1]);                           \
      *reinterpret_cast<unsigned int*>(&xbuf[(XP) ^ 1][xwidx0]) = p0;          \
      *reinterpret_cast<unsigned int*>(&xbuf[(XP) ^ 1][xwidx1]) = p1;          \
    }                                                                          \
    ELEM(1, wlB, 0);                                                           \
    wlA = wlA2; wlB = wlB2;                                                    \
    LBAR();                                                                    \
  } while (0)

__global__ __launch_bounds__(512, 2) void lstm_fused_kernel(
    const float* __restrict__ x,     // [2048,256,128]
    const float* __restrict__ w_ih,  // [512,128]
    const float* __restrict__ w_hh,  // [512,128]
    const float* __restrict__ b_ih,  // [512]
    const float* __restrict__ b_hh,  // [512]
    const float* __restrict__ w_lin, // [1, 256*128]
    const float* __restrict__ b_lin, // [1]
    float* __restrict__ out)         // [2048]
{
    // xbuf: bf16 [16 rows][128 k], swizzle ^((row&7)<<3)  (8 batch x 2 steps)
    // hbuf: COMPACT bf16 [8 rows][128 k], swizzle ^(row<<3); row == batch row
    __shared__ __align__(16) unsigned short xbuf[2][16 * 128];
    __shared__ __align__(16) unsigned short hbuf[2][8 * 128];
    __shared__ float redout[8][8];

    const int tid  = threadIdx.x;
    const int wave = tid >> 6;      // 0..7
    const int lane = tid & 63;
    const int c16  = lane & 15;
    const int kq   = lane >> 4;     // 0..3
    const int row0 = blockIdx.x * 8;
    const int hid  = wave * 16 + c16;
    // compact h row read by this lane: pairs (c16, c16|2) broadcast
    const int hcr  = ((c16 >> 2) << 1) | (c16 & 1);

    // zero hbuf (h0 = 0): 2*8*128*2B = 4KB = 512 threads x 8B
    reinterpret_cast<unsigned long long*>(hbuf)[tid] = 0ull;

    // ---- weights -> register B-fragments (bf16) ----
    // wave w, gate tile n, col c16: logical gate G = n*128 + w*16 + c16
    // K: kt<4 -> w_ih, kt>=4 -> w_hh
    short8 bq[8][4];
#pragma unroll
    for (int kt = 0; kt < 8; ++kt) {
#pragma unroll
        for (int n = 0; n < 4; ++n) {
            const int G  = n * 128 + wave * 16 + c16;
            const int k0 = kt * 32 + kq * 8;
            const float* src = (kt < 4) ? (w_ih + G * 128 + k0)
                                        : (w_hh + G * 128 + (k0 - 128));
            f32x4 lo = *reinterpret_cast<const f32x4*>(src);
            f32x4 hi = *reinterpret_cast<const f32x4*>(src + 4);
            bq[kt][n] = pack8(lo, hi);
        }
    }
    float bias[4];
#pragma unroll
    for (int n = 0; n < 4; ++n) {
        const int G = n * 128 + wave * 16 + c16;
        bias[n] = b_ih[G] + b_hh[G];
    }

    // x staging: wave w owns batch row b=w; step-parity s at A-row r0 + 2s,
    // r0 = 4*(w>>1) + (w&1)
    const int r0s    = 4 * (wave >> 1) + (wave & 1);
    const int r1s    = r0s + 2;
    const int xwidx0 = (r0s * 128 + lane * 2) ^ ((r0s & 7) << 3);
    const int xwidx1 = (r1s * 128 + lane * 2) ^ ((r1s & 7) << 3);
    const float* xrow = x + (size_t)(row0 + wave) * T_STEPS * 128 + lane * 2;

    // prologue: stage steps 0,1 into xbuf[0]
    {
        f32x2 v0 = *reinterpret_cast<const f32x2*>(xrow);
        f32x2 v1 = *reinterpret_cast<const f32x2*>(xrow + 128);
        unsigned int p0 = cvt_pk_bf16(v0[0], v0[1]);
        unsigned int p1 = cvt_pk_bf16(v1[0], v1[1]);
        *reinterpret_cast<unsigned int*>(&xbuf[0][xwidx0]) = p0;
        *reinterpret_cast<unsigned int*>(&xbuf[0][xwidx1]) = p1;
    }

    // lane (c16,kq) owns batch rows {2kq+j}, j=0,1 -> compact h rows 2kq+j
    float cstate[2] = {0.f, 0.f};
    float accout[2] = {0.f, 0.f};
    float wlA = w_lin[hid];
    float wlB = w_lin[128 + hid];
    float wlA2, wlB2;
    f32x2 nx0, nx1;
    const int hwidx0 = ((2 * kq + 0) * 128 + hid) ^ ((2 * kq + 0) << 3);
    const int hwidx1 = ((2 * kq + 1) * 128 + hid) ^ ((2 * kq + 1) << 3);

    __syncthreads();  // zeros + x[0..1] staged

    for (int t = 0; t < T_STEPS; t += 4) {
        GROUP(t, 0);
        GROUP(t + 2, 1);
    }

    // ---- reduce accout over hid: 16-lane tree, then across waves ----
#pragma unroll
    for (int r = 0; r < 2; ++r) {
        float v = accout[r];
        v += __shfl_xor(v, 1);
        v += __shfl_xor(v, 2);
        v += __shfl_xor(v, 4);
        v += __shfl_xor(v, 8);
        if (c16 == 0) redout[wave][2 * kq + r] = v;  // batch row 2kq+r
    }
    __syncthreads();
    if (tid < 8) {
        float s = b_lin[0];
#pragma unroll
        for (int w = 0; w < 8; ++w) s += redout[w][tid];
        out[row0 + tid] = s;
    }
}

extern "C" void kernel_launch(void* const* d_in, const int* in_sizes, int n_in,
                              void* d_out, int out_size, void* d_ws, size_t ws_size,
                              hipStream_t stream) {
    const float* x     = (const float*)d_in[0];
    const float* w_ih  = (const float*)d_in[1];
    const float* w_hh  = (const float*)d_in[2];
    const float* b_ih  = (const float*)d_in[3];
    const float* b_hh  = (const float*)d_in[4];
    const float* w_lin = (const float*)d_in[5];
    const float* b_lin = (const float*)d_in[6];
    float* out = (float*)d_out;

    lstm_fused_kernel<<<256, 512, 0, stream>>>(x, w_ih, w_hh, b_ih, b_hh, w_lin, b_lin, out);
}